// Round 11
// baseline (165.341 us; speedup 1.0000x reference)
//
#include <hip/hip_runtime.h>
#include <hip/hip_bf16.h>

#define NB 4
#define C 128
#define N 4096          // 64*64
#define EPS 1e-6f
#define PW 80           // padded image width (x in [-8, 71])
#define PIMG 5120       // 64*80 padded pixels per image

typedef float f32x4 __attribute__((ext_vector_type(4)));
typedef short bf16x8 __attribute__((ext_vector_type(8)));
typedef unsigned short ushort_t;
typedef unsigned int uint_t;

__device__ __forceinline__ ushort_t f2bf(float f) {
  __hip_bfloat16 h = __float2bfloat16(f);
  return *reinterpret_cast<ushort_t*>(&h);
}

struct alignas(8) us4 { ushort_t a, b, c, d; };

// ====== prep_misc: frag-order bf16 weights + both 32x32 convs + dsum zero ======
__device__ __forceinline__ void conv_body(const float* __restrict__ x,
                                          const float* __restrict__ w,
                                          const float* __restrict__ bias,
                                          float* __restrict__ out,
                                          int n, int o0, int b, int CIN) {
  const float* xb = x + (size_t)(b * CIN) * 1024 + n;
  float a0 = 0.f, a1 = 0.f, a2 = 0.f, a3 = 0.f;
  for (int c = 0; c < CIN; ++c) {
    float xv = xb[(size_t)c * 1024];
    a0 += w[(o0 + 0) * CIN + c] * xv;
    a1 += w[(o0 + 1) * CIN + c] * xv;
    a2 += w[(o0 + 2) * CIN + c] * xv;
    a3 += w[(o0 + 3) * CIN + c] * xv;
  }
  size_t ob = ((size_t)b * 128 + o0) * 1024 + n;
  out[ob]        = a0 + bias[o0];
  out[ob + 1024] = a1 + bias[o0 + 1];
  out[ob + 2048] = a2 + bias[o0 + 2];
  out[ob + 3072] = a3 + bias[o0 + 3];
}

__global__ void prep_misc(const float* __restrict__ edge_f, const float* __restrict__ w_align,
                          const float* __restrict__ b_align,
                          const float* __restrict__ fused_f, const float* __restrict__ w_fal,
                          const float* __restrict__ b_fal,
                          const float* __restrict__ wq, const float* __restrict__ wk,
                          const float* __restrict__ wf,
                          ushort_t* __restrict__ wqf, ushort_t* __restrict__ wkf,
                          ushort_t* __restrict__ wff,
                          float* __restrict__ edge32, float* __restrict__ fused32,
                          float* __restrict__ dsum) {
  int bx = blockIdx.x, t = threadIdx.x;
  if (bx < 64) {
    if (bx == 0 && t < NB) dsum[t] = 0.f;
    int c = bx * 256 + t;                  // chunk id 0..16383
    int lane = c & 63;
    int mrow = lane & 15, quad = lane >> 4;
    if (c < 4096) {                        // wqf: 16 tiles x 4 kslots (K=128, concat folded)
      int grp = c >> 6;
      int tile = grp >> 2, kslot = grp & 3;
      int o = tile * 16 + mrow, k0 = kslot * 32 + quad * 8;
      const float* s = wq + o * 256 + k0;
      ushort_t* d = wqf + (size_t)c * 8;
#pragma unroll
      for (int j = 0; j < 8; ++j) d[j] = f2bf(s[j] + s[128 + j]);
    } else if (c < 12288) {                // wkf: 16 tiles x 8 kslots (K=256)
      int c2 = c - 4096;
      int grp = c2 >> 6;
      int tile = grp >> 3, kslot = grp & 7;
      int o = tile * 16 + mrow, k0 = kslot * 32 + quad * 8;
      const float* s = wk + o * 256 + k0;
      ushort_t* d = wkf + (size_t)c2 * 8;
#pragma unroll
      for (int j = 0; j < 8; ++j) d[j] = f2bf(s[j]);
    } else {                               // wff: 8 tiles x 8 kslots (K=256)
      int c2 = c - 12288;
      int grp = c2 >> 6;
      int tile = grp >> 3, kslot = grp & 7;
      int o = tile * 16 + mrow, k0 = kslot * 32 + quad * 8;
      const float* s = wf + o * 256 + k0;
      ushort_t* d = wff + (size_t)c2 * 8;
#pragma unroll
      for (int j = 0; j < 8; ++j) d[j] = f2bf(s[j]);
    }
  } else if (bx < 576) {
    int j = bx - 64;
    conv_body(edge_f, w_align, b_align, edge32, (j & 3) * 256 + t, ((j >> 2) & 31) * 4, j >> 7, 64);
  } else {
    int j = bx - 576;
    conv_body(fused_f, w_fal, b_fal, fused32, (j & 3) * 256 + t, ((j >> 2) & 31) * 4, j >> 7, 128);
  }
}

// === prep_acts: upsample + cosine-sim + l2e partial + Q & V MFMA + transpose ====
// block = 16 px (quarter image row), all 128 ch. grid (256, NB) = 1024 blocks
// (4 blocks/CU for latency hiding). thread: px = t&15, cg = t>>4 (16 x 8ch).
__global__ __launch_bounds__(256) void prep_acts(const float* __restrict__ edge32,
                                                 const float* __restrict__ fused32,
                                                 const float* __restrict__ sem,
                                                 const ushort_t* __restrict__ wqf,
                                                 const ushort_t* __restrict__ wff,
                                                 const float* __restrict__ b_q,
                                                 ushort_t* __restrict__ xt_sem,
                                                 ushort_t* __restrict__ xt_fused,
                                                 float* __restrict__ simb,
                                                 float* __restrict__ l2e,
                                                 float* __restrict__ dsum,
                                                 ushort_t* __restrict__ qtb,
                                                 ushort_t* __restrict__ v2b) {
  int b = blockIdx.y, bx = blockIdx.x;
  int y = bx >> 2, xq = (bx & 3) * 16;
  int t = threadIdx.x;
  int px = t & 15, cg = t >> 4;
  int x = xq + px;
  int yy0 = (y & 1) ? (y >> 1) : (y >> 1) - 1;
  float fy = (y & 1) ? 0.25f : 0.75f;
  int y0c = max(yy0, 0), y1c = min(yy0 + 1, 31);
  int xx0 = (x & 1) ? (x >> 1) : (x >> 1) - 1;
  float fx = (x & 1) ? 0.25f : 0.75f;
  int x0c = max(xx0, 0), x1c = min(xx0 + 1, 31);

  __shared__ __align__(16) uint_t se[16][68], ssm[16][68], sf[16][68];
  __shared__ float red[4][3][16];
  __shared__ float simL[16];
  __shared__ __align__(16) ushort_t vstg[128 * 24];

  float ee = 0.f, ssum = 0.f, es = 0.f;
#pragma unroll
  for (int p = 0; p < 4; ++p) {           // 4 channel pairs (8 ch per thread)
    float evs[2], fvs[2], svs[2];
#pragma unroll
    for (int u = 0; u < 2; ++u) {
      int c = cg * 8 + p * 2 + u;
      const float* ip = edge32 + ((size_t)(b * 128 + c)) * 1024;
      float e00 = ip[y0c * 32 + x0c], e01 = ip[y0c * 32 + x1c];
      float e10 = ip[y1c * 32 + x0c], e11 = ip[y1c * 32 + x1c];
      float ev = (1.f - fy) * ((1.f - fx) * e00 + fx * e01) + fy * ((1.f - fx) * e10 + fx * e11);
      const float* fp = fused32 + ((size_t)(b * 128 + c)) * 1024;
      float f00 = fp[y0c * 32 + x0c], f01 = fp[y0c * 32 + x1c];
      float f10 = fp[y1c * 32 + x0c], f11 = fp[y1c * 32 + x1c];
      float fv = (1.f - fy) * ((1.f - fx) * f00 + fx * f01) + fy * ((1.f - fx) * f10 + fx * f11);
      float sv = sem[((size_t)(b * 128 + c)) * 4096 + y * 64 + x];
      ee += ev * ev; ssum += sv * sv; es += ev * sv;
      evs[u] = ev; fvs[u] = fv; svs[u] = sv;
    }
    int col = cg * 4 + p;
    se[px][col]  = (uint_t)f2bf(evs[0]) | ((uint_t)f2bf(evs[1]) << 16);
    sf[px][col]  = (uint_t)f2bf(fvs[0]) | ((uint_t)f2bf(fvs[1]) << 16);
    ssm[px][col] = (uint_t)f2bf(svs[0]) | ((uint_t)f2bf(svs[1]) << 16);
  }
  // in-wave reduce over the 4 cg-subgroups (lanes px, px+16, px+32, px+48)
  ee += __shfl_xor(ee, 16, 64); ee += __shfl_xor(ee, 32, 64);
  ssum += __shfl_xor(ssum, 16, 64); ssum += __shfl_xor(ssum, 32, 64);
  es += __shfl_xor(es, 16, 64); es += __shfl_xor(es, 32, 64);
  int w = t >> 6, lane = t & 63;
  int l15 = lane & 15, quad = lane >> 4;
  if (lane < 16) { red[w][0][lane] = ee; red[w][1][lane] = ssum; red[w][2][lane] = es; }
  __syncthreads();

  // bf16 n-major outputs (16 px x 64 uint = 1024 -> 4 reps)
  int base_n = b * 4096 + y * 64 + xq;
#pragma unroll
  for (int rep = 0; rep < 4; ++rep) {
    int d = rep * 256 + t;
    int r = d >> 6, cp = d & 63;
    ((uint_t*)xt_sem)[(size_t)(base_n + r) * 64 + cp] = ssm[r][cp];
    ((uint_t*)xt_fused)[(size_t)(base_n + r) * 64 + cp] = sf[r][cp];
  }
  if (t < 16) {
    float E = 0.f, S = 0.f, X = 0.f;
#pragma unroll
    for (int w2 = 0; w2 < 4; ++w2) { E += red[w2][0][t]; S += red[w2][1][t]; X += red[w2][2][t]; }
    float le = sqrtf(E), ls = sqrtf(S);
    float sv = (X / ((le + EPS) * (ls + EPS)) + 1.f) * 0.5f;
    simb[base_n + t] = sv;
    simL[t] = sv;
    l2e[base_n + t] = le;
    float pe = expf(le - 16.f);       // fixed-shift softmax partial (exact reassociation)
#pragma unroll
    for (int m2 = 8; m2; m2 >>= 1) pe += __shfl_xor(pe, m2, 64);   // lanes 0..15
    if (t == 0) atomicAdd(&dsum[b], pe);
  }
  __syncthreads();

  // ---- V = Wf @ [sem; fused] (MFMA); wave w: o-tiles {w, w+4}; 16 MFMAs ----
  {
    f32x4 vacc[2];
    vacc[0] = (f32x4){0.f,0.f,0.f,0.f};
    vacc[1] = (f32x4){0.f,0.f,0.f,0.f};
#pragma unroll
    for (int kk = 0; kk < 4; ++kk) {
      bf16x8 bfr = *(const bf16x8*)&ssm[l15][kk * 16 + quad * 4];
#pragma unroll
      for (int i = 0; i < 2; ++i) {
        bf16x8 afr = *(const bf16x8*)(wff + (size_t)(((w + i * 4) * 8 + kk) * 64 + lane) * 8);
        vacc[i] = __builtin_amdgcn_mfma_f32_16x16x32_bf16(afr, bfr, vacc[i], 0, 0, 0);
      }
    }
#pragma unroll
    for (int kk = 0; kk < 4; ++kk) {
      bf16x8 bfr = *(const bf16x8*)&sf[l15][kk * 16 + quad * 4];
#pragma unroll
      for (int i = 0; i < 2; ++i) {
        bf16x8 afr = *(const bf16x8*)(wff + (size_t)(((w + i * 4) * 8 + 4 + kk) * 64 + lane) * 8);
        vacc[i] = __builtin_amdgcn_mfma_f32_16x16x32_bf16(afr, bfr, vacc[i], 0, 0, 0);
      }
    }
#pragma unroll
    for (int i = 0; i < 2; ++i) {
#pragma unroll
      for (int r = 0; r < 4; ++r) {
        int ch = (w + i * 4) * 16 + quad * 4 + r;
        vstg[ch * 24 + l15] = f2bf(vacc[i][r]);
      }
    }
  }

  // ---- Q = sim * (Wq_folded @ edge) + b_q (MFMA); wave w: o-tiles w*4..w*4+3 ----
  {
    f32x4 qacc[4];
#pragma unroll
    for (int i = 0; i < 4; ++i) qacc[i] = (f32x4){0.f,0.f,0.f,0.f};
#pragma unroll
    for (int kk = 0; kk < 4; ++kk) {
      bf16x8 bfr = *(const bf16x8*)&se[l15][kk * 16 + quad * 4];
#pragma unroll
      for (int i = 0; i < 4; ++i) {
        bf16x8 afr = *(const bf16x8*)(wqf + (size_t)(((w * 4 + i) * 4 + kk) * 64 + lane) * 8);
        qacc[i] = __builtin_amdgcn_mfma_f32_16x16x32_bf16(afr, bfr, qacc[i], 0, 0, 0);
      }
    }
    float sv = simL[l15];
    int n = y * 64 + xq + l15;
#pragma unroll
    for (int i = 0; i < 4; ++i) {
      int o = (w * 4 + i) * 16 + quad * 4;
      float4 bq = *(const float4*)(b_q + o);
      us4 pk = { f2bf(sv * qacc[i][0] + bq.x), f2bf(sv * qacc[i][1] + bq.y),
                 f2bf(sv * qacc[i][2] + bq.z), f2bf(sv * qacc[i][3] + bq.w) };
      *(us4*)(qtb + ((size_t)b * N + n) * 256 + o) = pk;
    }
  }

  __syncthreads();
  // coalesced v2b stores (padded ch-major): 128 ch x 16 px = 2 b128 per ch
  int np0 = y * PW + 8 + xq;
  {
    int ch = t >> 1, seg = t & 1;
    *(bf16x8*)(v2b + ((size_t)b * 128 + ch) * PIMG + np0 + seg * 8) =
        *(const bf16x8*)&vstg[ch * 24 + seg * 8];
  }
}

// ============ gemm_k: K projection, half-row per block, 2-tile ILP ==============
__global__ __launch_bounds__(256) void gemm_k(const ushort_t* __restrict__ xt_sem,
                                              const ushort_t* __restrict__ xt_fused,
                                              const ushort_t* __restrict__ wkf,
                                              const float* __restrict__ b_k,
                                              const float* __restrict__ l2e,
                                              const float* __restrict__ dsum,
                                              ushort_t* __restrict__ ktb) {
  int bx = blockIdx.x, bI = blockIdx.y;
  int y = bx >> 1, xh = (bx & 1) * 32;
  int t = threadIdx.x, w = t >> 6, lane = t & 63;
  int mrow = lane & 15, quad = lane >> 4;
  __shared__ __align__(16) ushort_t stg[32 * 264];

  int n0 = y * 64 + xh, o0 = w * 64;
  float dscale = 4096.f / dsum[bI];
  for (int nt = 0; nt < 2; ++nt) {
    int n0t = n0 + nt * 16;
    const ushort_t* bS = xt_sem + ((size_t)bI * N + n0t + mrow) * 128 + quad * 8;
    const ushort_t* bF = xt_fused + ((size_t)bI * N + n0t + mrow) * 128 + quad * 8;
    f32x4 accL[4], accR[4];
#pragma unroll
    for (int i = 0; i < 4; ++i) { accL[i] = (f32x4){0.f,0.f,0.f,0.f}; accR[i] = (f32x4){0.f,0.f,0.f,0.f}; }
#pragma unroll
    for (int kk = 0; kk < 4; ++kk) {
      bf16x8 bfr = *(const bf16x8*)(bS + kk * 32);
#pragma unroll
      for (int i = 0; i < 4; ++i) {
        bf16x8 afr = *(const bf16x8*)(wkf + (size_t)((((w * 4 + i) * 8) + kk) * 64 + lane) * 8);
        accL[i] = __builtin_amdgcn_mfma_f32_16x16x32_bf16(afr, bfr, accL[i], 0, 0, 0);
      }
    }
#pragma unroll
    for (int kk = 0; kk < 4; ++kk) {
      bf16x8 bfr = *(const bf16x8*)(bF + kk * 32);
#pragma unroll
      for (int i = 0; i < 4; ++i) {
        bf16x8 afr = *(const bf16x8*)(wkf + (size_t)((((w * 4 + i) * 8) + 4 + kk) * 64 + lane) * 8);
        accR[i] = __builtin_amdgcn_mfma_f32_16x16x32_bf16(afr, bfr, accR[i], 0, 0, 0);
      }
    }
    int n = n0t + mrow;
    float dv = expf(l2e[bI * N + n] - 16.f) * dscale;
#pragma unroll
    for (int i = 0; i < 4; ++i) {
      int o = o0 + i * 16 + quad * 4;
      float4 bk = *(const float4*)(b_k + o);
      us4 pk = { f2bf(accL[i][0] * dv + accR[i][0] + bk.x),
                 f2bf(accL[i][1] * dv + accR[i][1] + bk.y),
                 f2bf(accL[i][2] * dv + accR[i][2] + bk.z),
                 f2bf(accL[i][3] * dv + accR[i][3] + bk.w) };
      *(us4*)&stg[(nt * 16 + mrow) * 264 + o] = pk;
    }
  }
  __syncthreads();
  int np0 = y * PW + 8 + xh;
#pragma unroll
  for (int r = 0; r < 4; ++r) {
    int cidx = r * 256 + t;
    int row = cidx >> 5, cc = cidx & 31;
    *(bf16x8*)(ktb + ((size_t)bI * PIMG + np0 + row) * 256 + cc * 8) =
        *(const bf16x8*)&stg[row * 264 + cc * 8];
  }
}

// ======== attention: 8x4 query tiles (2x K/V amortization), all-MFMA ============
__global__ __launch_bounds__(256) void attn_kernel(const ushort_t* __restrict__ qtb,
                                                   const ushort_t* __restrict__ ktb,
                                                   const ushort_t* __restrict__ v2b,
                                                   const float* __restrict__ b_fusion,
                                                   float* __restrict__ out) {
  // XCD swizzle: same (L & 7) -> same XCD; each XCD owns one (batch, y-half-band).
  int L = blockIdx.x;                          // 512 blocks
  int xcd = L & 7, j = L >> 3;                 // j in [0,64)
  int b = xcd >> 1;
  int ty0 = (((xcd & 1) << 3) + (j >> 3)) * 4; // 16 y-tiles of 4 rows
  int tx0 = (j & 7) * 8;                       // 8 x-tiles of 8 cols
  int y0 = max(ty0 - 5, 0), y1 = min(ty0 + 8, 63);
  int nh = y1 - y0 + 1;                        // 9..14
  int x0a = tx0 - 8, cb = tx0;                 // 24-wide window [tx0-8, tx0+15], 8-aligned
  int ntq = (nh * 3 + 1) >> 1;                 // 16-key tiles, <= 21
  int npv = (nh * 3 + 3) >> 2;                 // 32-key PV chunks, <= 11

  __shared__ ushort_t pst[32][352];            // P bf16 [q 32][key], 704B rows (16B mult)
  __shared__ float redm[4][2][16], reds[4][2][16];

  int t = threadIdx.x, w = t >> 6, lane = t & 63;
  int l15 = lane & 15, quad = lane >> 4;

  // zero tail gap [ntq*16, npv*32) for all 32 q (gap <= 16)
  int gap = npv * 32 - ntq * 16;
  for (int idx = t; idx < 32 * gap; idx += 256)
    pst[idx & 31][ntq * 16 + (idx >> 5)] = 0;

  // Q B-frags for both 8x2 subtiles, direct from qtb (held in regs)
  int n_s0 = (ty0 + (l15 >> 3)) * 64 + tx0 + (l15 & 7);
  int n_s1 = n_s0 + 128;                       // +2 rows
  bf16x8 qfr[2][8];
  {
    const ushort_t* q0 = qtb + ((size_t)b * N + n_s0) * 256 + quad * 8;
    const ushort_t* q1 = qtb + ((size_t)b * N + n_s1) * 256 + quad * 8;
#pragma unroll
    for (int ks = 0; ks < 8; ++ks) {
      qfr[0][ks] = *(const bf16x8*)(q0 + ks * 32);
      qfr[1][ks] = *(const bf16x8*)(q1 + ks * 32);
    }
  }
  int qx = tx0 + (l15 & 7);
  int qy0 = ty0 + (l15 >> 3);                  // subtile 0; subtile 1 = +2

  // ---- phase 1: QK^T; wave w: key-tiles w, w+4, ...; A (K) shared across subtiles
  const ushort_t* kb = ktb + (size_t)b * PIMG * 256;
  f32x4 sc[6][2];
#pragma unroll
  for (int i = 0; i < 6; ++i) {
    int tq = w + i * 4;
    if (tq >= ntq) break;
    int key = tq * 16 + l15;
    int ry = (key * 2731) >> 16;               // key / 24
    int rx = key - ry * 24;
    int yy = min(y0 + ry, 63);
    const ushort_t* krow = kb + (size_t)(yy * PW + cb + rx) * 256 + quad * 8;
    f32x4 a0 = (f32x4){0.f,0.f,0.f,0.f}, a1 = (f32x4){0.f,0.f,0.f,0.f};
#pragma unroll
    for (int ks = 0; ks < 8; ++ks) {
      bf16x8 afr = *(const bf16x8*)(krow + ks * 32);
      a0 = __builtin_amdgcn_mfma_f32_16x16x32_bf16(afr, qfr[0][ks], a0, 0, 0, 0);
      a1 = __builtin_amdgcn_mfma_f32_16x16x32_bf16(afr, qfr[1][ks], a1, 0, 0, 0);
    }
    sc[i][0] = a0; sc[i][1] = a1;
  }
  // ---- mask + scale + per-subtile max (lane: q=l15, key=tq*16+quad*4+r) ----
  float mymax0 = -1e30f, mymax1 = -1e30f;
#pragma unroll
  for (int i = 0; i < 6; ++i) {
    int tq = w + i * 4;
    if (tq >= ntq) break;
#pragma unroll
    for (int r = 0; r < 4; ++r) {
      int key = tq * 16 + quad * 4 + r;
      int ry = (key * 2731) >> 16;
      int rx = key - ry * 24;
      int x = x0a + rx;
      int dx = x - qx;
      bool xok = (dx >= -5) && (dx <= 5) && (x >= 0) && (x <= 63) && (ry < nh);
      int dy0 = y0 + ry - qy0;
      float s0 = (xok && dy0 >= -5 && dy0 <= 5) ? sc[i][0][r] * 0.0625f : -1e30f;
      int dy1 = dy0 - 2;
      float s1 = (xok && dy1 >= -5 && dy1 <= 5) ? sc[i][1][r] * 0.0625f : -1e30f;
      sc[i][0][r] = s0; sc[i][1][r] = s1;
      mymax0 = fmaxf(mymax0, s0); mymax1 = fmaxf(mymax1, s1);
    }
  }
  mymax0 = fmaxf(mymax0, __shfl_xor(mymax0, 16, 64));
  mymax0 = fmaxf(mymax0, __shfl_xor(mymax0, 32, 64));
  mymax1 = fmaxf(mymax1, __shfl_xor(mymax1, 16, 64));
  mymax1 = fmaxf(mymax1, __shfl_xor(mymax1, 32, 64));
  if (quad == 0) { redm[w][0][l15] = mymax0; redm[w][1][l15] = mymax1; }
  __syncthreads();
  float gmax0 = fmaxf(fmaxf(redm[0][0][l15], redm[1][0][l15]), fmaxf(redm[2][0][l15], redm[3][0][l15]));
  float gmax1 = fmaxf(fmaxf(redm[0][1][l15], redm[1][1][l15]), fmaxf(redm[2][1][l15], redm[3][1][l15]));
  float mysum0 = 0.f, mysum1 = 0.f;
#pragma unroll
  for (int i = 0; i < 6; ++i) {
    int tq = w + i * 4;
    if (tq >= ntq) break;
#pragma unroll
    for (int r = 0; r < 4; ++r) {
      float e0 = expf(sc[i][0][r] - gmax0);
      float e1 = expf(sc[i][1][r] - gmax1);
      sc[i][0][r] = e0; sc[i][1][r] = e1;
      mysum0 += e0; mysum1 += e1;
    }
  }
  mysum0 += __shfl_xor(mysum0, 16, 64); mysum0 += __shfl_xor(mysum0, 32, 64);
  mysum1 += __shfl_xor(mysum1, 16, 64); mysum1 += __shfl_xor(mysum1, 32, 64);
  if (quad == 0) { reds[w][0][l15] = mysum0; reds[w][1][l15] = mysum1; }
  // P -> LDS (packed u32 writes)
#pragma unroll
  for (int i = 0; i < 6; ++i) {
    int tq = w + i * 4;
    if (tq >= ntq) break;
    int kc = tq * 16 + quad * 4;
#pragma unroll
    for (int s = 0; s < 2; ++s) {
      uint_t p01 = (uint_t)f2bf(sc[i][s][0]) | ((uint_t)f2bf(sc[i][s][1]) << 16);
      uint_t p23 = (uint_t)f2bf(sc[i][s][2]) | ((uint_t)f2bf(sc[i][s][3]) << 16);
      *(uint_t*)(&pst[s * 16 + l15][kc]) = p01;
      *(uint_t*)(&pst[s * 16 + l15][kc + 2]) = p23;
    }
  }
  __syncthreads();

  float rinv0 = 1.f / (reds[0][0][l15] + reds[1][0][l15] + reds[2][0][l15] + reds[3][0][l15]);
  float rinv1 = 1.f / (reds[0][1][l15] + reds[1][1][l15] + reds[2][1][l15] + reds[3][1][l15]);

  // ---- phase 3: PV. A = V (direct global b128, shared across subtiles) ----
  const ushort_t* vb = v2b + (size_t)b * 128 * PIMG;
#pragma unroll
  for (int half = 0; half < 2; ++half) {
    int ch0 = half * 64 + w * 16;
    const ushort_t* vrow = vb + (size_t)(ch0 + l15) * PIMG;
    f32x4 acc0 = (f32x4){0.f,0.f,0.f,0.f}, acc1 = (f32x4){0.f,0.f,0.f,0.f};
    for (int ks = 0; ks < npv; ++ks) {
      int kst = ks * 32 + quad * 8;            // never crosses a 24-key row
      int ry = (kst * 2731) >> 16;
      int rxs = kst - ry * 24;
      int yy = min(y0 + ry, 63);
      bf16x8 av = *(const bf16x8*)(vrow + yy * PW + cb + rxs);
      bf16x8 bp0 = *(const bf16x8*)(&pst[l15][kst]);
      bf16x8 bp1 = *(const bf16x8*)(&pst[16 + l15][kst]);
      acc0 = __builtin_amdgcn_mfma_f32_16x16x32_bf16(av, bp0, acc0, 0, 0, 0);
      acc1 = __builtin_amdgcn_mfma_f32_16x16x32_bf16(av, bp1, acc1, 0, 0, 0);
    }
    int chg = ch0 + quad * 4;
    float4 bf4 = *(const float4*)(b_fusion + chg);
    float bfa[4] = {bf4.x, bf4.y, bf4.z, bf4.w};
#pragma unroll
    for (int r = 0; r < 4; ++r) {
      out[((size_t)b * 128 + chg + r) * N + n_s0] = acc0[r] * rinv0 + bfa[r];
      out[((size_t)b * 128 + chg + r) * N + n_s1] = acc1[r] * rinv1 + bfa[r];
    }
  }
}

extern "C" void kernel_launch(void* const* d_in, const int* in_sizes, int n_in,
                              void* d_out, int out_size, void* d_ws, size_t ws_size,
                              hipStream_t stream) {
  (void)in_sizes; (void)n_in; (void)out_size; (void)ws_size;
  const float* edge_f  = (const float*)d_in[0];
  const float* sem     = (const float*)d_in[1];
  const float* fused_f = (const float*)d_in[2];
  const float* w_align = (const float*)d_in[3];
  const float* b_align = (const float*)d_in[4];
  const float* w_fal   = (const float*)d_in[5];
  const float* b_fal   = (const float*)d_in[6];
  const float* w_q     = (const float*)d_in[7];
  const float* b_q     = (const float*)d_in[8];
  const float* w_k     = (const float*)d_in[9];
  const float* b_k     = (const float*)d_in[10];
  const float* w_fus   = (const float*)d_in[11];
  const float* b_fus   = (const float*)d_in[12];
  float* out = (float*)d_out;

  float* ws = (float*)d_ws;
  float* edge32   = ws;                              // 524288
  float* fused32  = ws + 524288;                     // 524288
  float* simb     = ws + 1048576;                    // 16384
  float* l2e      = ws + 1064960;                    // 16384
  float* dsum     = ws + 1081344;                    // 4 (+pad)
  ushort_t* xt_sem   = (ushort_t*)(ws + 1097728);    // 2097152 us
  ushort_t* xt_fused = (ushort_t*)(ws + 2146304);    // 2097152 us
  ushort_t* wqf      = (ushort_t*)(ws + 3194880);    // 32768 us (frag-order)
  ushort_t* wkf      = (ushort_t*)(ws + 3211264);    // 65536 us
  ushort_t* wff      = (ushort_t*)(ws + 3244032);    // 32768 us
  ushort_t* qtb      = (ushort_t*)(ws + 3260416);    // 4194304 us [b][n][256]
  ushort_t* ktb      = (ushort_t*)(ws + 5357568);    // 5242880 us [b][5120][256] padded
  ushort_t* v2b      = (ushort_t*)(ws + 7979008);    // 2621440 us [b][128][5120] padded
  // high-water ~37 MB (pad cols hold harness poison: finite bf16, masked in attn)

  prep_misc<<<1088, 256, 0, stream>>>(edge_f, w_align, b_align, fused_f, w_fal, b_fal,
                                      w_q, w_k, w_fus, wqf, wkf, wff, edge32, fused32, dsum);
  prep_acts<<<dim3(256, NB), 256, 0, stream>>>(edge32, fused32, sem, wqf, wff, b_q,
                                               xt_sem, xt_fused, simb, l2e, dsum, qtb, v2b);
  gemm_k<<<dim3(128, NB), 256, 0, stream>>>(xt_sem, xt_fused, wkf, b_k, l2e, dsum, ktb);
  attn_kernel<<<512, 256, 0, stream>>>(qtb, ktb, v2b, b_fus, out);
}